// Round 1
// baseline (1505.371 us; speedup 1.0000x reference)
//
#include <hip/hip_runtime.h>
#include <hip/hip_bf16.h>
#include <hip/hip_cooperative_groups.h>
#include <math.h>
#include <stdint.h>

namespace cg = cooperative_groups;
#define DEVINL __device__ __forceinline__

constexpr int BB    = 16;
constexpr int TT    = 50;
constexpr int VV    = 50000;
constexpr int HIDN  = 200;
constexpr int G3    = 600;      // 3*HID
constexpr int NROWS = BB * TT;  // 800
constexpr int KP    = 416;      // K=400 padded to mult of 32
constexpr int MP    = 896;      // 800 padded to mult of 128
constexpr int NP    = 50048;    // 50000 padded to mult of 128
constexpr int NTILES = NP / 128; // 391
constexpr int MTILES = MP / 128; // 7
constexpr int OUTW  = VV + HIDN; // 50200

typedef __attribute__((ext_vector_type(4))) float f32x4;
typedef __attribute__((ext_vector_type(8))) short bf16x8;

DEVINL unsigned short f2bf(float v) {
    __hip_bfloat16 b = __float2bfloat16(v);
    return *reinterpret_cast<unsigned short*>(&b);
}

DEVINL void gl_lds16(const void* g, void* lds) {
    __builtin_amdgcn_global_load_lds((const __attribute__((address_space(1))) void*)g,
                                     (__attribute__((address_space(3))) void*)lds,
                                     16, 0, 0);
}

// ---------------------------------------------------------------- W_attn^T
__global__ void __launch_bounds__(256) k_wattnT(const float* __restrict__ W,
                                                float* __restrict__ WT) {
    int i = blockIdx.x * 256 + threadIdx.x;
    if (i < 200 * 200) {
        int k = i / 200, n = i - k * 200;
        WT[(size_t)n * 200 + k] = W[i];
    }
}

// ------------------------------------------- small fp32 GEMM: C = A @ B^T + bias
// Brows: [N][200] row-major (k-contiguous). MODE 0: plain A rows;
// MODE 1: A row = embed[y[m]]; MODE 2: A row = h1[(m/200)*201 + m%200].
template <int MODE>
__global__ void __launch_bounds__(256) k_small_gemm(const float* __restrict__ A,
                                                    const float* __restrict__ Brows,
                                                    const float* __restrict__ bias,
                                                    float* __restrict__ C,
                                                    const int* __restrict__ yidx,
                                                    int M, int N) {
    __shared__ float Ash[32][200];
    __shared__ float Bsh[32][200];
    int m0 = blockIdx.x * 32, n0 = blockIdx.y * 32;
    int tid = threadIdx.x;
    for (int i = tid; i < 32 * 200; i += 256) {
        int r = i / 200, k = i - r * 200;
        int gm = m0 + r;
        const float* src;
        if (MODE == 0)      src = A + (size_t)gm * 200;
        else if (MODE == 1) src = A + (size_t)yidx[gm] * 200;
        else { int bb = gm / 200, ss = gm - bb * 200; src = A + ((size_t)bb * 201 + ss) * 200; }
        Ash[r][k] = src[k];
    }
    for (int i = tid; i < 32 * 200; i += 256) {
        int r = i / 200, k = i - r * 200;
        int gn = n0 + r;
        Bsh[r][k] = (gn < N) ? Brows[(size_t)gn * 200 + k] : 0.f;
    }
    __syncthreads();
    int tx = tid & 15, ty = tid >> 4;
    float acc00 = 0, acc01 = 0, acc10 = 0, acc11 = 0;
    #pragma unroll 4
    for (int k = 0; k < 200; ++k) {
        float a0 = Ash[ty][k], a1 = Ash[ty + 16][k];
        float b0 = Bsh[tx][k], b1 = Bsh[tx + 16][k];
        acc00 += a0 * b0; acc01 += a0 * b1;
        acc10 += a1 * b0; acc11 += a1 * b1;
    }
    int gm0 = m0 + ty, gm1 = m0 + ty + 16;
    int gn0 = n0 + tx, gn1 = n0 + tx + 16;
    if (gn0 < N) { C[(size_t)gm0 * N + gn0] = acc00 + bias[gn0];
                   C[(size_t)gm1 * N + gn0] = acc10 + bias[gn0]; }
    if (gn1 < N) { C[(size_t)gm0 * N + gn1] = acc01 + bias[gn1];
                   C[(size_t)gm1 * N + gn1] = acc11 + bias[gn1]; }
}

// ---------------------------------------------------------------- GRU (cooperative)
// grid 128 = 16 batches x 8 j-chunks of 25. W_hh chunk resident in LDS.
__global__ void __launch_bounds__(256) k_gru(const float* __restrict__ gi,
                                             const float* __restrict__ W_hh,
                                             const float* __restrict__ b_hh,
                                             const float* __restrict__ h1,
                                             float* __restrict__ h2,
                                             float* __restrict__ hbuf) {
    __shared__ float wsh[75][200];
    __shared__ float bsh[75];
    __shared__ __align__(16) float hsh[200];
    int blk = blockIdx.x;
    int b = blk >> 3, qc = blk & 7, j0 = qc * 25;
    int tid = threadIdx.x;

    for (int i = tid; i < 75 * 200; i += 256) {
        int r = i / 200, k = i - r * 200;
        int g = r / 25, jl = r - g * 25;
        wsh[r][k] = W_hh[((size_t)(g * 200 + j0 + jl)) * 200 + k];
    }
    if (tid < 75) {
        int g = tid / 25, jl = tid - g * 25;
        bsh[tid] = b_hh[g * 200 + j0 + jl];
    }
    if (tid < 25)
        hbuf[(size_t)b * 200 + j0 + tid] = h1[((size_t)b * 201 + 200) * 200 + j0 + tid];

    cg::this_grid().sync();

    int jl = tid >> 3, p = tid & 7, ks = p * 25;
    for (int t = 0; t < TT; ++t) {
        const float* hsrc = hbuf + (size_t)(t & 1) * BB * 200 + (size_t)b * 200;
        if (tid < 50)
            reinterpret_cast<float4*>(hsh)[tid] = reinterpret_cast<const float4*>(hsrc)[tid];
        __syncthreads();

        float rs = 0.f, zs = 0.f, ns = 0.f;
        if (jl < 25) {
            #pragma unroll
            for (int kk = 0; kk < 25; ++kk) {
                int k = ks + kk;
                float h = hsh[k];
                rs += wsh[jl][k] * h;
                zs += wsh[25 + jl][k] * h;
                ns += wsh[50 + jl][k] * h;
            }
        }
        rs += __shfl_xor(rs, 1); zs += __shfl_xor(zs, 1); ns += __shfl_xor(ns, 1);
        rs += __shfl_xor(rs, 2); zs += __shfl_xor(zs, 2); ns += __shfl_xor(ns, 2);
        rs += __shfl_xor(rs, 4); zs += __shfl_xor(zs, 4); ns += __shfl_xor(ns, 4);

        if (jl < 25 && p == 0) {
            int j = j0 + jl;
            const float* girow = gi + ((size_t)b * TT + t) * G3;
            float hr = rs + bsh[jl];
            float hz = zs + bsh[25 + jl];
            float hn = ns + bsh[50 + jl];
            float r = 1.f / (1.f + __expf(-(girow[j] + hr)));
            float z = 1.f / (1.f + __expf(-(girow[200 + j] + hz)));
            float n = tanhf(girow[400 + j] + r * hn);
            float hnew = (1.f - z) * n + z * hsh[j];
            hbuf[(size_t)((t + 1) & 1) * BB * 200 + (size_t)b * 200 + j] = hnew;
            h2[((size_t)b * TT + t) * 200 + j] = hnew;
        }
        cg::this_grid().sync();
    }
}

// ---------------------------------------------------------------- fused attention + gate
__global__ void __launch_bounds__(256) k_attn(const float* __restrict__ q,
                                              const float* __restrict__ kv,
                                              const float* __restrict__ h2,
                                              const float* __restrict__ W_gate,
                                              const float* __restrict__ b_gate,
                                              float* __restrict__ out,
                                              float* __restrict__ gbuf,
                                              unsigned short* __restrict__ s2b) {
    int row = blockIdx.x;
    int b = row / TT;
    int tid = threadIdx.x;
    __shared__ __align__(16) float qsh[200];
    __shared__ __align__(16) float h2sh[200];
    __shared__ float ash[200];
    __shared__ float csh[200];
    __shared__ float red[8];

    if (tid < 50) {
        reinterpret_cast<float4*>(qsh)[tid]  = reinterpret_cast<const float4*>(q  + (size_t)row * 200)[tid];
        reinterpret_cast<float4*>(h2sh)[tid] = reinterpret_cast<const float4*>(h2 + (size_t)row * 200)[tid];
    }
    __syncthreads();

    const float* kvb = kv + (size_t)b * 200 * 200;
    float dval = -__builtin_inff();
    if (tid < 200) {
        const float4* kr = reinterpret_cast<const float4*>(kvb + (size_t)tid * 200);
        float s = 0.f;
        #pragma unroll 5
        for (int k4 = 0; k4 < 50; ++k4) {
            float4 kvv = kr[k4];
            float4 qv = reinterpret_cast<float4*>(qsh)[k4];
            s += kvv.x * qv.x + kvv.y * qv.y + kvv.z * qv.z + kvv.w * qv.w;
        }
        dval = s * 0.07071067811865475f;  // 1/sqrt(200)
    }
    // block max
    float m = dval;
    for (int o = 32; o; o >>= 1) m = fmaxf(m, __shfl_xor(m, o));
    if ((tid & 63) == 0) red[tid >> 6] = m;
    __syncthreads();
    m = fmaxf(fmaxf(red[0], red[1]), fmaxf(red[2], red[3]));
    // block sum of exp
    float e = (tid < 200) ? __expf(dval - m) : 0.f;
    float ssum = e;
    for (int o = 32; o; o >>= 1) ssum += __shfl_xor(ssum, o);
    if ((tid & 63) == 0) red[4 + (tid >> 6)] = ssum;
    __syncthreads();
    float Ssum = red[4] + red[5] + red[6] + red[7];
    float logS = logf(Ssum);
    float p1v = dval - m - logS;
    if (tid < 200) ash[tid] = e / Ssum;
    __syncthreads();

    // c = sum_s a_s * kv[s][:]
    if (tid < 200) {
        float c = 0.f;
        #pragma unroll 4
        for (int s = 0; s < 200; ++s) c += ash[s] * kvb[(size_t)s * 200 + tid];
        csh[tid] = c;
    }
    __syncthreads();

    // gate g = s2 . W_gate + b_gate
    float gv = 0.f;
    if (tid < 200) gv = h2sh[tid] * W_gate[tid] + csh[tid] * W_gate[200 + tid];
    for (int o = 32; o; o >>= 1) gv += __shfl_xor(gv, o);
    if ((tid & 63) == 0) red[tid >> 6] = gv;
    __syncthreads();
    float g = red[0] + red[1] + red[2] + red[3] + b_gate[0];

    if (tid == 0) gbuf[row] = g;
    if (tid < 200) out[(size_t)row * OUTW + VV + tid] = (1.f - g) * p1v;

    // s2 row -> bf16, K padded to 416 with zeros
    if (tid < 208) {
        int k = tid * 2;
        float v0 = (k < 200) ? h2sh[k] : (k < 400) ? csh[k - 200] : 0.f;
        float v1 = (k + 1 < 200) ? h2sh[k + 1] : (k + 1 < 400) ? csh[k + 1 - 200] : 0.f;
        unsigned int pk = (unsigned int)f2bf(v0) | ((unsigned int)f2bf(v1) << 16);
        reinterpret_cast<unsigned int*>(s2b + (size_t)row * KP)[tid] = pk;
    }
}

// ---------------------------------------------------------------- W_out -> bf16 transposed
__global__ void __launch_bounds__(256) k_woutT(const float* __restrict__ W,
                                               unsigned short* __restrict__ WT) {
    __shared__ unsigned short tile[400][66];  // +2 pad vs bank conflicts
    int n0 = blockIdx.x * 64;
    int tid = threadIdx.x;
    for (int i = tid; i < 400 * 64; i += 256) {
        int k = i >> 6, n = i & 63;
        int gn = n0 + n;
        float v = (gn < VV) ? W[(size_t)k * VV + gn] : 0.f;
        tile[k][n] = f2bf(v);
    }
    __syncthreads();
    int n = tid >> 2, part = tid & 3;
    unsigned int* dst = reinterpret_cast<unsigned int*>(WT + (size_t)(n0 + n) * KP);
    #pragma unroll 4
    for (int u = 0; u < 52; ++u) {
        int k = part * 104 + u * 2;
        unsigned int lo = (k < 400) ? (unsigned int)tile[k][n] : 0u;
        unsigned int hi = (k + 1 < 400) ? (unsigned int)tile[k + 1][n] : 0u;
        dst[part * 52 + u] = lo | (hi << 16);
    }
}

// ---------------------------------------------------------------- big bf16 MFMA GEMM
// pass 1: per-(row, ntile) online (max, sumexp) partials.
// pass 2: recompute logits, write g*(logit - logZ) to out.
__global__ void __launch_bounds__(256) k_gemm_big(int pass,
        const unsigned short* __restrict__ Ab, const unsigned short* __restrict__ Bb,
        const float* __restrict__ b_out, float2* __restrict__ partials,
        const float* __restrict__ logZs, const float* __restrict__ gbuf,
        float* __restrict__ out) {
    __shared__ __align__(16) unsigned short Ash[128 * 32];
    __shared__ __align__(16) unsigned short Bsh[128 * 32];
    __shared__ float redsh[128][2][2];
    __shared__ float zsh[128], gsh[128];

    const int m0 = blockIdx.x * 128, n0 = blockIdx.y * 128;
    const int tid = threadIdx.x;
    const int lane = tid & 63, wid = tid >> 6;
    const int wr = wid >> 1, wc = wid & 1;
    const int rq = lane >> 4, r15 = lane & 15;

    if (pass == 2 && tid < 128) {
        int gm = m0 + tid;
        zsh[tid] = (gm < NROWS) ? logZs[gm] : 0.f;
        gsh[tid] = (gm < NROWS) ? gbuf[gm] : 0.f;
    }

    const int c2 = tid + 256;
    const unsigned short* a1 = Ab + (size_t)(m0 + (tid >> 2)) * KP + (tid & 3) * 8;
    const unsigned short* a2 = Ab + (size_t)(m0 + (c2 >> 2)) * KP + (c2 & 3) * 8;
    const unsigned short* b1 = Bb + (size_t)(n0 + (tid >> 2)) * KP + (tid & 3) * 8;
    const unsigned short* b2 = Bb + (size_t)(n0 + (c2 >> 2)) * KP + (c2 & 3) * 8;
    unsigned short* ldsA1 = Ash + wid * 512;
    unsigned short* ldsA2 = Ash + wid * 512 + 2048;
    unsigned short* ldsB1 = Bsh + wid * 512;
    unsigned short* ldsB2 = Bsh + wid * 512 + 2048;

    f32x4 zero = {0.f, 0.f, 0.f, 0.f};
    f32x4 acc[4][4];
    #pragma unroll
    for (int i = 0; i < 4; ++i)
        #pragma unroll
        for (int j = 0; j < 4; ++j) acc[i][j] = zero;

    const bf16x8* A8 = reinterpret_cast<const bf16x8*>(Ash);
    const bf16x8* B8 = reinterpret_cast<const bf16x8*>(Bsh);

    for (int kt = 0; kt < KP / 32; ++kt) {
        const int ko = kt * 32;
        gl_lds16(a1 + ko, ldsA1);
        gl_lds16(a2 + ko, ldsA2);
        gl_lds16(b1 + ko, ldsB1);
        gl_lds16(b2 + ko, ldsB2);
        __syncthreads();   // drains vmcnt -> LDS tile ready
        bf16x8 af[4], bfr[4];
        #pragma unroll
        for (int mi = 0; mi < 4; ++mi) af[mi] = A8[(wr * 64 + mi * 16 + r15) * 4 + rq];
        #pragma unroll
        for (int ni = 0; ni < 4; ++ni) bfr[ni] = B8[(wc * 64 + ni * 16 + r15) * 4 + rq];
        #pragma unroll
        for (int mi = 0; mi < 4; ++mi)
            #pragma unroll
            for (int ni = 0; ni < 4; ++ni)
                acc[mi][ni] = __builtin_amdgcn_mfma_f32_16x16x32_bf16(af[mi], bfr[ni], acc[mi][ni], 0, 0, 0);
        __syncthreads();   // all reads done before next overwrite
    }

    float bias[4]; bool nok[4]; int gn[4];
    #pragma unroll
    for (int ni = 0; ni < 4; ++ni) {
        gn[ni] = n0 + wc * 64 + ni * 16 + r15;
        nok[ni] = gn[ni] < VV;
        bias[ni] = nok[ni] ? b_out[gn[ni]] : 0.f;
    }

    if (pass == 1) {
        #pragma unroll
        for (int mi = 0; mi < 4; ++mi) {
            #pragma unroll
            for (int r = 0; r < 4; ++r) {
                float v[4]; float mx = -__builtin_inff();
                #pragma unroll
                for (int ni = 0; ni < 4; ++ni) {
                    v[ni] = nok[ni] ? (acc[mi][ni][r] + bias[ni]) : -__builtin_inff();
                    mx = fmaxf(mx, v[ni]);
                }
                #pragma unroll
                for (int o = 1; o < 16; o <<= 1) mx = fmaxf(mx, __shfl_xor(mx, o));
                float se = 0.f;
                #pragma unroll
                for (int ni = 0; ni < 4; ++ni) se += nok[ni] ? __expf(v[ni] - mx) : 0.f;
                #pragma unroll
                for (int o = 1; o < 16; o <<= 1) se += __shfl_xor(se, o);
                int ml = wr * 64 + mi * 16 + rq * 4 + r;
                if (r15 == 0) { redsh[ml][wc][0] = mx; redsh[ml][wc][1] = se; }
            }
        }
        __syncthreads();
        if (tid < 128) {
            float m1 = redsh[tid][0][0], s1 = redsh[tid][0][1];
            float m2 = redsh[tid][1][0], s2 = redsh[tid][1][1];
            float mm = fmaxf(m1, m2);
            float ss = s1 * __expf(m1 - mm) + s2 * __expf(m2 - mm);
            partials[(size_t)(m0 + tid) * NTILES + blockIdx.y] = float2{mm, ss};
        }
    } else {
        #pragma unroll
        for (int mi = 0; mi < 4; ++mi) {
            #pragma unroll
            for (int r = 0; r < 4; ++r) {
                int ml = wr * 64 + mi * 16 + rq * 4 + r;
                int gm = m0 + ml;
                if (gm < NROWS) {
                    float gz = gsh[ml], lz = zsh[ml];
                    #pragma unroll
                    for (int ni = 0; ni < 4; ++ni)
                        if (nok[ni])
                            out[(size_t)gm * OUTW + gn[ni]] = gz * (acc[mi][ni][r] + bias[ni] - lz);
                }
            }
        }
    }
}

// ---------------------------------------------------------------- row reduce -> logZ
__global__ void __launch_bounds__(128) k_rowred(const float2* __restrict__ partials,
                                                float* __restrict__ logZs) {
    int row = blockIdx.x;
    int tid = threadIdx.x;
    float m = -__builtin_inff(), s = 0.f;
    for (int t = tid; t < NTILES; t += 128) {
        float2 p = partials[(size_t)row * NTILES + t];
        if (p.y > 0.f) {
            float nm = fmaxf(m, p.x);
            s = s * __expf(m - nm) + p.y * __expf(p.x - nm);
            m = nm;
        }
    }
    for (int o = 32; o; o >>= 1) {
        float om = __shfl_xor(m, o), os = __shfl_xor(s, o);
        float nm = fmaxf(m, om);
        s = s * __expf(m - nm) + os * __expf(om - nm);
        m = nm;
    }
    __shared__ float ms[2], ss[2];
    if ((tid & 63) == 0) { ms[tid >> 6] = m; ss[tid >> 6] = s; }
    __syncthreads();
    if (tid == 0) {
        float nm = fmaxf(ms[0], ms[1]);
        float S = ss[0] * __expf(ms[0] - nm) + ss[1] * __expf(ms[1] - nm);
        logZs[row] = nm + logf(S);
    }
}

// ----------------------------------------------------------------
extern "C" void kernel_launch(void* const* d_in, const int* in_sizes, int n_in,
                              void* d_out, int out_size, void* d_ws, size_t ws_size,
                              hipStream_t stream) {
    const int*   y      = (const int*)  d_in[0];
    const float* h1     = (const float*)d_in[1];
    const float* embed  = (const float*)d_in[2];
    const float* W_ih   = (const float*)d_in[3];
    const float* W_hh   = (const float*)d_in[4];
    const float* b_ih   = (const float*)d_in[5];
    const float* b_hh   = (const float*)d_in[6];
    const float* W_attn = (const float*)d_in[7];
    const float* b_attn = (const float*)d_in[8];
    const float* W_gate = (const float*)d_in[9];
    const float* b_gate = (const float*)d_in[10];
    const float* W_out  = (const float*)d_in[11];
    const float* b_out  = (const float*)d_in[12];
    float* out = (float*)d_out;

    char* wp = (char*)d_ws;
    auto alloc = [&](size_t bytes) {
        char* p = wp;
        wp += (bytes + 255) & ~(size_t)255;
        return p;
    };
    float* gi     = (float*)alloc((size_t)NROWS * G3 * 4);
    float* h2     = (float*)alloc((size_t)NROWS * HIDN * 4);
    float* hbuf   = (float*)alloc((size_t)2 * BB * HIDN * 4);
    float* wattnT = (float*)alloc((size_t)200 * 200 * 4);
    float* q      = (float*)alloc((size_t)NROWS * 200 * 4);
    float* kv     = (float*)alloc((size_t)BB * 200 * 200 * 4);
    float* gbuf   = (float*)alloc((size_t)NROWS * 4);
    float* logZs  = (float*)alloc((size_t)NROWS * 4);
    float2* partials      = (float2*)alloc((size_t)MP * NTILES * 8);
    unsigned short* s2b   = (unsigned short*)alloc((size_t)MP * KP * 2);
    unsigned short* woutT = (unsigned short*)alloc((size_t)NP * KP * 2);

    k_wattnT<<<dim3(157), dim3(256), 0, stream>>>(W_attn, wattnT);
    k_small_gemm<1><<<dim3(25, 19), dim3(256), 0, stream>>>(embed, W_ih, b_ih, gi, y, NROWS, G3);
    {
        const float* gi_c = gi;
        float* h2_p = h2;
        float* hb_p = hbuf;
        void* args[] = { (void*)&gi_c, (void*)&W_hh, (void*)&b_hh,
                         (void*)&h1, (void*)&h2_p, (void*)&hb_p };
        hipLaunchCooperativeKernel((void*)k_gru, dim3(128), dim3(256), args, 0, stream);
    }
    k_small_gemm<0><<<dim3(25, 7),  dim3(256), 0, stream>>>(h2, wattnT, b_attn, q,  nullptr, NROWS, 200);
    k_small_gemm<2><<<dim3(100, 7), dim3(256), 0, stream>>>(h1, wattnT, b_attn, kv, nullptr, BB * 200, 200);
    k_attn<<<dim3(NROWS), dim3(256), 0, stream>>>(q, kv, h2, W_gate, b_gate, out, gbuf, s2b);
    k_woutT<<<dim3(NP / 64), dim3(256), 0, stream>>>(W_out, woutT);
    k_gemm_big<<<dim3(MTILES, NTILES), dim3(256), 0, stream>>>(1, s2b, woutT, b_out, partials, logZs, gbuf, out);
    k_rowred<<<dim3(NROWS), dim3(128), 0, stream>>>(partials, logZs);
    k_gemm_big<<<dim3(MTILES, NTILES), dim3(256), 0, stream>>>(2, s2b, woutT, b_out, partials, logZs, gbuf, out);
}

// Round 5
// 844.357 us; speedup vs baseline: 1.7829x; 1.7829x over previous
//
#include <hip/hip_runtime.h>
#include <hip/hip_bf16.h>
#include <math.h>
#include <stdint.h>

#define DEVINL __device__ __forceinline__

constexpr int BB    = 16;
constexpr int TT    = 50;
constexpr int VV    = 50000;
constexpr int HIDN  = 200;
constexpr int G3    = 600;      // 3*HID
constexpr int NROWS = BB * TT;  // 800
constexpr int KP    = 416;      // K=400 padded to mult of 32
constexpr int MP    = 896;      // 800 padded to mult of 128
constexpr int NP    = 50048;    // 50000 padded to mult of 128
constexpr int NTILES = NP / 128; // 391
constexpr int MTILES = MP / 128; // 7
constexpr int OUTW  = VV + HIDN; // 50200

typedef __attribute__((ext_vector_type(4))) float f32x4;
typedef __attribute__((ext_vector_type(8))) short bf16x8;

DEVINL unsigned short f2bf(float v) {
    __hip_bfloat16 b = __float2bfloat16(v);
    return *reinterpret_cast<unsigned short*>(&b);
}

DEVINL void gl_lds16(const void* g, void* lds) {
    __builtin_amdgcn_global_load_lds((const __attribute__((address_space(1))) void*)g,
                                     (__attribute__((address_space(3))) void*)lds,
                                     16, 0, 0);
}

// ---------------------------------------------------------------- W_attn^T
__global__ void __launch_bounds__(256) k_wattnT(const float* __restrict__ W,
                                                float* __restrict__ WT) {
    int i = blockIdx.x * 256 + threadIdx.x;
    if (i < 200 * 200) {
        int k = i / 200, n = i - k * 200;
        WT[(size_t)n * 200 + k] = W[i];
    }
}

// ------------------------------------------- small fp32 GEMM: C = A @ B^T + bias
template <int MODE>
__global__ void __launch_bounds__(256) k_small_gemm(const float* __restrict__ A,
                                                    const float* __restrict__ Brows,
                                                    const float* __restrict__ bias,
                                                    float* __restrict__ C,
                                                    const int* __restrict__ yidx,
                                                    int M, int N) {
    __shared__ float Ash[32][200];
    __shared__ float Bsh[32][200];
    int m0 = blockIdx.x * 32, n0 = blockIdx.y * 32;
    int tid = threadIdx.x;
    for (int i = tid; i < 32 * 200; i += 256) {
        int r = i / 200, k = i - r * 200;
        int gm = m0 + r;
        const float* src;
        if (MODE == 0)      src = A + (size_t)gm * 200;
        else if (MODE == 1) src = A + (size_t)yidx[gm] * 200;
        else { int bb = gm / 200, ss = gm - bb * 200; src = A + ((size_t)bb * 201 + ss) * 200; }
        Ash[r][k] = src[k];
    }
    for (int i = tid; i < 32 * 200; i += 256) {
        int r = i / 200, k = i - r * 200;
        int gn = n0 + r;
        Bsh[r][k] = (gn < N) ? Brows[(size_t)gn * 200 + k] : 0.f;
    }
    __syncthreads();
    int tx = tid & 15, ty = tid >> 4;
    float acc00 = 0, acc01 = 0, acc10 = 0, acc11 = 0;
    #pragma unroll 4
    for (int k = 0; k < 200; ++k) {
        float a0 = Ash[ty][k], a1 = Ash[ty + 16][k];
        float b0 = Bsh[tx][k], b1 = Bsh[tx + 16][k];
        acc00 += a0 * b0; acc01 += a0 * b1;
        acc10 += a1 * b0; acc11 += a1 * b1;
    }
    int gm0 = m0 + ty, gm1 = m0 + ty + 16;
    int gn0 = n0 + tx, gn1 = n0 + tx + 16;
    if (gn0 < N) { C[(size_t)gm0 * N + gn0] = acc00 + bias[gn0];
                   C[(size_t)gm1 * N + gn0] = acc10 + bias[gn0]; }
    if (gn1 < N) { C[(size_t)gm0 * N + gn1] = acc01 + bias[gn1];
                   C[(size_t)gm1 * N + gn1] = acc11 + bias[gn1]; }
}

// ---------------------------------------------------------------- GRU: 1 block per batch
// 512 threads. Thread t<512 holds full fp32 row u=t of W_hh in 50 float4 regs.
// Rows 512..599 (88 rows, n-gate j in [112,200)) live in LDS; threads 0..175
// compute them with a 2-way k-split + shfl reduce. No cross-block sync at all.
__global__ void __launch_bounds__(512, 2) k_gru(const float* __restrict__ gi,
                                                const float* __restrict__ W_hh,
                                                const float* __restrict__ b_hh,
                                                const float* __restrict__ h1,
                                                float* __restrict__ h2) {
    __shared__ float wlds[88][200];      // 70.4 KB
    __shared__ __align__(16) float hsh[200];
    __shared__ float pre[600];
    __shared__ float bsh[600];

    const int b = blockIdx.x;
    const int t = threadIdx.x;

    // --- prologue: weights into registers -------------------------------
    float4 wv[50];
    {
        const float4* wrow = reinterpret_cast<const float4*>(W_hh + (size_t)t * 200);
        #pragma unroll
        for (int i = 0; i < 50; ++i) wv[i] = wrow[i];
    }
    // rows 512..599 into LDS (coalesced)
    for (int i = t; i < 88 * 200; i += 512) {
        int r = i / 200, k = i - r * 200;
        wlds[r][k] = W_hh[(size_t)(512 + r) * 200 + k];
    }
    for (int i = t; i < 600; i += 512) bsh[i] = b_hh[i];   // full 600 biases
    if (t < 200) hsh[t] = h1[((size_t)b * 201 + 200) * 200 + t];
    __syncthreads();

    const float4* hsh4 = reinterpret_cast<const float4*>(hsh);
    const int lr = t >> 1, lq = t & 1;          // LDS-row worker mapping (t<176)

    for (int step = 0; step < TT; ++step) {
        // prefetch gi for the activation phase (latency hides under dots)
        float gr = 0.f, gz = 0.f, gn_ = 0.f, hold = 0.f;
        if (t < 200) {
            const float* girow = gi + ((size_t)b * TT + step) * G3 + t;
            gr  = girow[0];
            gz  = girow[200];
            gn_ = girow[400];
            hold = hsh[t];
        }

        // register-row dot: pre-activation for output u = t
        float a0 = 0.f, a1 = 0.f, a2 = 0.f, a3 = 0.f;
        #pragma unroll
        for (int i = 0; i < 50; ++i) {
            float4 hv = hsh4[i];
            a0 += wv[i].x * hv.x;
            a1 += wv[i].y * hv.y;
            a2 += wv[i].z * hv.z;
            a3 += wv[i].w * hv.w;
        }
        float acc = (a0 + a1) + (a2 + a3);
        pre[t] = acc;

        // LDS-row dots: outputs 512 + lr, split k in halves of 100
        if (t < 176) {
            const float4* wr4 = reinterpret_cast<const float4*>(&wlds[lr][lq * 100]);
            const float4* hh4 = hsh4 + lq * 25;
            float c0 = 0.f, c1 = 0.f, c2 = 0.f, c3 = 0.f;
            #pragma unroll
            for (int i = 0; i < 25; ++i) {
                float4 wvv = wr4[i];
                float4 hv  = hh4[i];
                c0 += wvv.x * hv.x;
                c1 += wvv.y * hv.y;
                c2 += wvv.z * hv.z;
                c3 += wvv.w * hv.w;
            }
            float cc = (c0 + c1) + (c2 + c3);
            cc += __shfl_xor(cc, 1);
            if (lq == 0) pre[512 + lr] = cc;
        }
        __syncthreads();

        if (t < 200) {
            float pr = gr  + pre[t]       + bsh[t];
            float pz = gz  + pre[200 + t] + bsh[200 + t];
            float hn = pre[400 + t] + bsh[400 + t];
            float r = 1.f / (1.f + __expf(-pr));
            float z = 1.f / (1.f + __expf(-pz));
            float n = tanhf(gn_ + r * hn);
            float hnew = (1.f - z) * n + z * hold;
            hsh[t] = hnew;
            h2[((size_t)b * TT + step) * 200 + t] = hnew;
        }
        __syncthreads();
    }
}

// ---------------------------------------------------------------- fused attention + gate
__global__ void __launch_bounds__(256) k_attn(const float* __restrict__ q,
                                              const float* __restrict__ kv,
                                              const float* __restrict__ h2,
                                              const float* __restrict__ W_gate,
                                              const float* __restrict__ b_gate,
                                              float* __restrict__ out,
                                              float* __restrict__ gbuf,
                                              unsigned short* __restrict__ s2b) {
    int row = blockIdx.x;
    int b = row / TT;
    int tid = threadIdx.x;
    __shared__ __align__(16) float qsh[200];
    __shared__ __align__(16) float h2sh[200];
    __shared__ float ash[200];
    __shared__ float csh[200];
    __shared__ float red[8];

    if (tid < 50) {
        reinterpret_cast<float4*>(qsh)[tid]  = reinterpret_cast<const float4*>(q  + (size_t)row * 200)[tid];
        reinterpret_cast<float4*>(h2sh)[tid] = reinterpret_cast<const float4*>(h2 + (size_t)row * 200)[tid];
    }
    __syncthreads();

    const float* kvb = kv + (size_t)b * 200 * 200;
    float dval = -__builtin_inff();
    if (tid < 200) {
        const float4* kr = reinterpret_cast<const float4*>(kvb + (size_t)tid * 200);
        float s = 0.f;
        #pragma unroll 5
        for (int k4 = 0; k4 < 50; ++k4) {
            float4 kvv = kr[k4];
            float4 qv = reinterpret_cast<float4*>(qsh)[k4];
            s += kvv.x * qv.x + kvv.y * qv.y + kvv.z * qv.z + kvv.w * qv.w;
        }
        dval = s * 0.07071067811865475f;  // 1/sqrt(200)
    }
    float m = dval;
    for (int o = 32; o; o >>= 1) m = fmaxf(m, __shfl_xor(m, o));
    if ((tid & 63) == 0) red[tid >> 6] = m;
    __syncthreads();
    m = fmaxf(fmaxf(red[0], red[1]), fmaxf(red[2], red[3]));
    float e = (tid < 200) ? __expf(dval - m) : 0.f;
    float ssum = e;
    for (int o = 32; o; o >>= 1) ssum += __shfl_xor(ssum, o);
    if ((tid & 63) == 0) red[4 + (tid >> 6)] = ssum;
    __syncthreads();
    float Ssum = red[4] + red[5] + red[6] + red[7];
    float logS = logf(Ssum);
    float p1v = dval - m - logS;
    if (tid < 200) ash[tid] = e / Ssum;
    __syncthreads();

    if (tid < 200) {
        float c = 0.f;
        #pragma unroll 4
        for (int s = 0; s < 200; ++s) c += ash[s] * kvb[(size_t)s * 200 + tid];
        csh[tid] = c;
    }
    __syncthreads();

    float gv = 0.f;
    if (tid < 200) gv = h2sh[tid] * W_gate[tid] + csh[tid] * W_gate[200 + tid];
    for (int o = 32; o; o >>= 1) gv += __shfl_xor(gv, o);
    if ((tid & 63) == 0) red[tid >> 6] = gv;
    __syncthreads();
    float g = red[0] + red[1] + red[2] + red[3] + b_gate[0];

    if (tid == 0) gbuf[row] = g;
    if (tid < 200) out[(size_t)row * OUTW + VV + tid] = (1.f - g) * p1v;

    if (tid < 208) {
        int k = tid * 2;
        float v0 = (k < 200) ? h2sh[k] : (k < 400) ? csh[k - 200] : 0.f;
        float v1 = (k + 1 < 200) ? h2sh[k + 1] : (k + 1 < 400) ? csh[k + 1 - 200] : 0.f;
        unsigned int pk = (unsigned int)f2bf(v0) | ((unsigned int)f2bf(v1) << 16);
        reinterpret_cast<unsigned int*>(s2b + (size_t)row * KP)[tid] = pk;
    }
}

// ---------------------------------------------------------------- W_out -> bf16 transposed
__global__ void __launch_bounds__(256) k_woutT(const float* __restrict__ W,
                                               unsigned short* __restrict__ WT) {
    __shared__ unsigned short tile[400][66];
    int n0 = blockIdx.x * 64;
    int tid = threadIdx.x;
    for (int i = tid; i < 400 * 64; i += 256) {
        int k = i >> 6, n = i & 63;
        int gn = n0 + n;
        float v = (gn < VV) ? W[(size_t)k * VV + gn] : 0.f;
        tile[k][n] = f2bf(v);
    }
    __syncthreads();
    int n = tid >> 2, part = tid & 3;
    unsigned int* dst = reinterpret_cast<unsigned int*>(WT + (size_t)(n0 + n) * KP);
    #pragma unroll 4
    for (int u = 0; u < 52; ++u) {
        int k = part * 104 + u * 2;
        unsigned int lo = (k < 400) ? (unsigned int)tile[k][n] : 0u;
        unsigned int hi = (k + 1 < 400) ? (unsigned int)tile[k + 1][n] : 0u;
        dst[part * 52 + u] = lo | (hi << 16);
    }
}

// ---------------------------------------------------------------- big bf16 MFMA GEMM
__global__ void __launch_bounds__(256) k_gemm_big(int pass,
        const unsigned short* __restrict__ Ab, const unsigned short* __restrict__ Bb,
        const float* __restrict__ b_out, float2* __restrict__ partials,
        const float* __restrict__ logZs, const float* __restrict__ gbuf,
        float* __restrict__ out) {
    __shared__ __align__(16) unsigned short Ash[128 * 32];
    __shared__ __align__(16) unsigned short Bsh[128 * 32];
    __shared__ float redsh[128][2][2];
    __shared__ float zsh[128], gsh[128];

    const int m0 = blockIdx.x * 128, n0 = blockIdx.y * 128;
    const int tid = threadIdx.x;
    const int lane = tid & 63, wid = tid >> 6;
    const int wr = wid >> 1, wc = wid & 1;
    const int rq = lane >> 4, r15 = lane & 15;

    if (pass == 2 && tid < 128) {
        int gm = m0 + tid;
        zsh[tid] = (gm < NROWS) ? logZs[gm] : 0.f;
        gsh[tid] = (gm < NROWS) ? gbuf[gm] : 0.f;
    }

    const int c2 = tid + 256;
    const unsigned short* a1 = Ab + (size_t)(m0 + (tid >> 2)) * KP + (tid & 3) * 8;
    const unsigned short* a2 = Ab + (size_t)(m0 + (c2 >> 2)) * KP + (c2 & 3) * 8;
    const unsigned short* b1 = Bb + (size_t)(n0 + (tid >> 2)) * KP + (tid & 3) * 8;
    const unsigned short* b2 = Bb + (size_t)(n0 + (c2 >> 2)) * KP + (c2 & 3) * 8;
    unsigned short* ldsA1 = Ash + wid * 512;
    unsigned short* ldsA2 = Ash + wid * 512 + 2048;
    unsigned short* ldsB1 = Bsh + wid * 512;
    unsigned short* ldsB2 = Bsh + wid * 512 + 2048;

    f32x4 zero = {0.f, 0.f, 0.f, 0.f};
    f32x4 acc[4][4];
    #pragma unroll
    for (int i = 0; i < 4; ++i)
        #pragma unroll
        for (int j = 0; j < 4; ++j) acc[i][j] = zero;

    const bf16x8* A8 = reinterpret_cast<const bf16x8*>(Ash);
    const bf16x8* B8 = reinterpret_cast<const bf16x8*>(Bsh);

    for (int kt = 0; kt < KP / 32; ++kt) {
        const int ko = kt * 32;
        gl_lds16(a1 + ko, ldsA1);
        gl_lds16(a2 + ko, ldsA2);
        gl_lds16(b1 + ko, ldsB1);
        gl_lds16(b2 + ko, ldsB2);
        __syncthreads();
        bf16x8 af[4], bfr[4];
        #pragma unroll
        for (int mi = 0; mi < 4; ++mi) af[mi] = A8[(wr * 64 + mi * 16 + r15) * 4 + rq];
        #pragma unroll
        for (int ni = 0; ni < 4; ++ni) bfr[ni] = B8[(wc * 64 + ni * 16 + r15) * 4 + rq];
        #pragma unroll
        for (int mi = 0; mi < 4; ++mi)
            #pragma unroll
            for (int ni = 0; ni < 4; ++ni)
                acc[mi][ni] = __builtin_amdgcn_mfma_f32_16x16x32_bf16(af[mi], bfr[ni], acc[mi][ni], 0, 0, 0);
        __syncthreads();
    }

    float bias[4]; bool nok[4]; int gn[4];
    #pragma unroll
    for (int ni = 0; ni < 4; ++ni) {
        gn[ni] = n0 + wc * 64 + ni * 16 + r15;
        nok[ni] = gn[ni] < VV;
        bias[ni] = nok[ni] ? b_out[gn[ni]] : 0.f;
    }

    if (pass == 1) {
        #pragma unroll
        for (int mi = 0; mi < 4; ++mi) {
            #pragma unroll
            for (int r = 0; r < 4; ++r) {
                float v[4]; float mx = -__builtin_inff();
                #pragma unroll
                for (int ni = 0; ni < 4; ++ni) {
                    v[ni] = nok[ni] ? (acc[mi][ni][r] + bias[ni]) : -__builtin_inff();
                    mx = fmaxf(mx, v[ni]);
                }
                #pragma unroll
                for (int o = 1; o < 16; o <<= 1) mx = fmaxf(mx, __shfl_xor(mx, o));
                float se = 0.f;
                #pragma unroll
                for (int ni = 0; ni < 4; ++ni) se += nok[ni] ? __expf(v[ni] - mx) : 0.f;
                #pragma unroll
                for (int o = 1; o < 16; o <<= 1) se += __shfl_xor(se, o);
                int ml = wr * 64 + mi * 16 + rq * 4 + r;
                if (r15 == 0) { redsh[ml][wc][0] = mx; redsh[ml][wc][1] = se; }
            }
        }
        __syncthreads();
        if (tid < 128) {
            float m1 = redsh[tid][0][0], s1 = redsh[tid][0][1];
            float m2 = redsh[tid][1][0], s2 = redsh[tid][1][1];
            float mm = fmaxf(m1, m2);
            float ss = s1 * __expf(m1 - mm) + s2 * __expf(m2 - mm);
            partials[(size_t)(m0 + tid) * NTILES + blockIdx.y] = float2{mm, ss};
        }
    } else {
        #pragma unroll
        for (int mi = 0; mi < 4; ++mi) {
            #pragma unroll
            for (int r = 0; r < 4; ++r) {
                int ml = wr * 64 + mi * 16 + rq * 4 + r;
                int gm = m0 + ml;
                if (gm < NROWS) {
                    float gz = gsh[ml], lz = zsh[ml];
                    #pragma unroll
                    for (int ni = 0; ni < 4; ++ni)
                        if (nok[ni])
                            out[(size_t)gm * OUTW + gn[ni]] = gz * (acc[mi][ni][r] + bias[ni] - lz);
                }
            }
        }
    }
}

// ---------------------------------------------------------------- row reduce -> logZ
__global__ void __launch_bounds__(128) k_rowred(const float2* __restrict__ partials,
                                                float* __restrict__ logZs) {
    int row = blockIdx.x;
    int tid = threadIdx.x;
    float m = -__builtin_inff(), s = 0.f;
    for (int t = tid; t < NTILES; t += 128) {
        float2 p = partials[(size_t)row * NTILES + t];
        if (p.y > 0.f) {
            float nm = fmaxf(m, p.x);
            s = s * __expf(m - nm) + p.y * __expf(p.x - nm);
            m = nm;
        }
    }
    for (int o = 32; o; o >>= 1) {
        float om = __shfl_xor(m, o), os = __shfl_xor(s, o);
        float nm = fmaxf(m, om);
        s = s * __expf(m - nm) + os * __expf(om - nm);
        m = nm;
    }
    __shared__ float ms[2], ss[2];
    if ((tid & 63) == 0) { ms[tid >> 6] = m; ss[tid >> 6] = s; }
    __syncthreads();
    if (tid == 0) {
        float nm = fmaxf(ms[0], ms[1]);
        float S = ss[0] * __expf(ms[0] - nm) + ss[1] * __expf(ms[1] - nm);
        logZs[row] = nm + logf(S);
    }
}

// ----------------------------------------------------------------
extern "C" void kernel_launch(void* const* d_in, const int* in_sizes, int n_in,
                              void* d_out, int out_size, void* d_ws, size_t ws_size,
                              hipStream_t stream) {
    const int*   y      = (const int*)  d_in[0];
    const float* h1     = (const float*)d_in[1];
    const float* embed  = (const float*)d_in[2];
    const float* W_ih   = (const float*)d_in[3];
    const float* W_hh   = (const float*)d_in[4];
    const float* b_ih   = (const float*)d_in[5];
    const float* b_hh   = (const float*)d_in[6];
    const float* W_attn = (const float*)d_in[7];
    const float* b_attn = (const float*)d_in[8];
    const float* W_gate = (const float*)d_in[9];
    const float* b_gate = (const float*)d_in[10];
    const float* W_out  = (const float*)d_in[11];
    const float* b_out  = (const float*)d_in[12];
    float* out = (float*)d_out;

    char* wp = (char*)d_ws;
    auto alloc = [&](size_t bytes) {
        char* p = wp;
        wp += (bytes + 255) & ~(size_t)255;
        return p;
    };
    float* gi     = (float*)alloc((size_t)NROWS * G3 * 4);
    float* h2     = (float*)alloc((size_t)NROWS * HIDN * 4);
    float* wattnT = (float*)alloc((size_t)200 * 200 * 4);
    float* q      = (float*)alloc((size_t)NROWS * 200 * 4);
    float* kv     = (float*)alloc((size_t)BB * 200 * 200 * 4);
    float* gbuf   = (float*)alloc((size_t)NROWS * 4);
    float* logZs  = (float*)alloc((size_t)NROWS * 4);
    float2* partials      = (float2*)alloc((size_t)MP * NTILES * 8);
    unsigned short* s2b   = (unsigned short*)alloc((size_t)MP * KP * 2);
    unsigned short* woutT = (unsigned short*)alloc((size_t)NP * KP * 2);

    k_wattnT<<<dim3(157), dim3(256), 0, stream>>>(W_attn, wattnT);
    k_small_gemm<1><<<dim3(25, 19), dim3(256), 0, stream>>>(embed, W_ih, b_ih, gi, y, NROWS, G3);
    k_gru<<<dim3(BB), dim3(512), 0, stream>>>(gi, W_hh, b_hh, h1, h2);
    k_small_gemm<0><<<dim3(25, 7),  dim3(256), 0, stream>>>(h2, wattnT, b_attn, q,  nullptr, NROWS, 200);
    k_small_gemm<2><<<dim3(100, 7), dim3(256), 0, stream>>>(h1, wattnT, b_attn, kv, nullptr, BB * 200, 200);
    k_attn<<<dim3(NROWS), dim3(256), 0, stream>>>(q, kv, h2, W_gate, b_gate, out, gbuf, s2b);
    k_woutT<<<dim3(NP / 64), dim3(256), 0, stream>>>(W_out, woutT);
    k_gemm_big<<<dim3(MTILES, NTILES), dim3(256), 0, stream>>>(1, s2b, woutT, b_out, partials, logZs, gbuf, out);
    k_rowred<<<dim3(NROWS), dim3(128), 0, stream>>>(partials, logZs);
    k_gemm_big<<<dim3(MTILES, NTILES), dim3(256), 0, stream>>>(2, s2b, woutT, b_out, partials, logZs, gbuf, out);
}

// Round 6
// 674.156 us; speedup vs baseline: 2.2330x; 1.2525x over previous
//
#include <hip/hip_runtime.h>
#include <hip/hip_bf16.h>
#include <math.h>
#include <stdint.h>

#define DEVINL __device__ __forceinline__

constexpr int BB    = 16;
constexpr int TT    = 50;
constexpr int VV    = 50000;
constexpr int HIDN  = 200;
constexpr int G3    = 600;      // 3*HID
constexpr int NROWS = BB * TT;  // 800
constexpr int KP    = 416;      // K=400 padded to mult of 32
constexpr int MP    = 896;      // 800 padded to mult of 128
constexpr int NP    = 50048;    // 50000 padded to mult of 128
constexpr int NTILES = NP / 128; // 391
constexpr int MTILES = MP / 128; // 7
constexpr int OUTW  = VV + HIDN; // 50200
constexpr int WBLKS = NP / 64;   // 782 wout-transpose blocks

typedef __attribute__((ext_vector_type(4))) float f32x4;
typedef __attribute__((ext_vector_type(8))) short bf16x8;

DEVINL unsigned short f2bf(float v) {
    __hip_bfloat16 b = __float2bfloat16(v);
    return *reinterpret_cast<unsigned short*>(&b);
}
DEVINL float bflo(unsigned u) { return __uint_as_float(u << 16); }
DEVINL float bfhi(unsigned u) { return __uint_as_float(u & 0xffff0000u); }

DEVINL void gl_lds16(const void* g, void* lds) {
    __builtin_amdgcn_global_load_lds((const __attribute__((address_space(1))) void*)g,
                                     (__attribute__((address_space(3))) void*)lds,
                                     16, 0, 0);
}

// ---------------------------------------------------------------- W_attn^T
__global__ void __launch_bounds__(256) k_wattnT(const float* __restrict__ W,
                                                float* __restrict__ WT) {
    int i = blockIdx.x * 256 + threadIdx.x;
    if (i < 200 * 200) {
        int k = i / 200, n = i - k * 200;
        WT[(size_t)n * 200 + k] = W[i];
    }
}

// ------------------------------------------- small fp32 GEMM: C = A @ B^T + bias
template <int MODE>
__global__ void __launch_bounds__(256) k_small_gemm(const float* __restrict__ A,
                                                    const float* __restrict__ Brows,
                                                    const float* __restrict__ bias,
                                                    float* __restrict__ C,
                                                    const int* __restrict__ yidx,
                                                    int M, int N) {
    __shared__ float Ash[32][200];
    __shared__ float Bsh[32][200];
    int m0 = blockIdx.x * 32, n0 = blockIdx.y * 32;
    int tid = threadIdx.x;
    for (int i = tid; i < 32 * 200; i += 256) {
        int r = i / 200, k = i - r * 200;
        int gm = m0 + r;
        const float* src;
        if (MODE == 0)      src = A + (size_t)gm * 200;
        else if (MODE == 1) src = A + (size_t)yidx[gm] * 200;
        else { int bb = gm / 200, ss = gm - bb * 200; src = A + ((size_t)bb * 201 + ss) * 200; }
        Ash[r][k] = src[k];
    }
    for (int i = tid; i < 32 * 200; i += 256) {
        int r = i / 200, k = i - r * 200;
        int gn = n0 + r;
        Bsh[r][k] = (gn < N) ? Brows[(size_t)gn * 200 + k] : 0.f;
    }
    __syncthreads();
    int tx = tid & 15, ty = tid >> 4;
    float acc00 = 0, acc01 = 0, acc10 = 0, acc11 = 0;
    #pragma unroll 4
    for (int k = 0; k < 200; ++k) {
        float a0 = Ash[ty][k], a1 = Ash[ty + 16][k];
        float b0 = Bsh[tx][k], b1 = Bsh[tx + 16][k];
        acc00 += a0 * b0; acc01 += a0 * b1;
        acc10 += a1 * b0; acc11 += a1 * b1;
    }
    int gm0 = m0 + ty, gm1 = m0 + ty + 16;
    int gn0 = n0 + tx, gn1 = n0 + tx + 16;
    if (gn0 < N) { C[(size_t)gm0 * N + gn0] = acc00 + bias[gn0];
                   C[(size_t)gm1 * N + gn0] = acc10 + bias[gn0]; }
    if (gn1 < N) { C[(size_t)gm0 * N + gn1] = acc01 + bias[gn1];
                   C[(size_t)gm1 * N + gn1] = acc11 + bias[gn1]; }
}

// ---------------------------------------------------------------- fused GRU + W_out transpose
// blocks 0..15: GRU, one block per batch, 512 threads.
//   Thread t holds W_hh row t as 25 uint4 of packed bf16 (100 VGPR — fits, no spill).
//   Rows 512..599 stay fp32 in LDS, handled by threads 0..175 (2-way k-split).
// blocks 16..: W_out fp32 [400][50000] -> bf16 transposed [50048][416], coalesced both sides.
__global__ void __launch_bounds__(512, 2) k_gru_wout(const float* __restrict__ gi,
                                                     const float* __restrict__ W_hh,
                                                     const float* __restrict__ b_hh,
                                                     const float* __restrict__ h1,
                                                     float* __restrict__ h2,
                                                     const float* __restrict__ W_out,
                                                     unsigned short* __restrict__ WT) {
    __shared__ float wlds[88][200];      // 70.4 KB (gru)
    __shared__ __align__(16) float hsh[200];
    __shared__ float pre[600];
    __shared__ float bsh[600];
    __shared__ unsigned short tile[400][66];  // 52.8 KB (wout)

    const int t = threadIdx.x;

    if (blockIdx.x >= BB) {
        // ---------------- W_out transpose path ----------------
        int n0 = (blockIdx.x - BB) * 64;
        for (int i = t; i < 400 * 64; i += 512) {
            int k = i >> 6, n = i & 63;
            int gn = n0 + n;
            float v = (gn < VV) ? W_out[(size_t)k * VV + gn] : 0.f;
            tile[k][n] = f2bf(v);
        }
        __syncthreads();
        // 64 rows x 208 dwords, linear -> consecutive lanes write consecutive dwords
        for (int i = t; i < 64 * 208; i += 512) {
            int n = i / 208, dw = i - n * 208;
            int k = dw * 2;
            unsigned int lo = (k < 400) ? (unsigned int)tile[k][n] : 0u;
            unsigned int hi = (k + 1 < 400) ? (unsigned int)tile[k + 1][n] : 0u;
            reinterpret_cast<unsigned int*>(WT + (size_t)(n0 + n) * KP)[dw] = lo | (hi << 16);
        }
        return;
    }

    // ---------------- GRU path ----------------
    const int b = blockIdx.x;

    // weights row t -> 25 uint4 of bf16 pairs (static indexing, stays in VGPRs)
    uint4 wb[25];
    {
        const float4* wrow = reinterpret_cast<const float4*>(W_hh + (size_t)t * 200);
        #pragma unroll
        for (int i = 0; i < 25; ++i) {
            float4 a = wrow[2 * i], c = wrow[2 * i + 1];
            wb[i].x = (unsigned)f2bf(a.x) | ((unsigned)f2bf(a.y) << 16);
            wb[i].y = (unsigned)f2bf(a.z) | ((unsigned)f2bf(a.w) << 16);
            wb[i].z = (unsigned)f2bf(c.x) | ((unsigned)f2bf(c.y) << 16);
            wb[i].w = (unsigned)f2bf(c.z) | ((unsigned)f2bf(c.w) << 16);
        }
    }
    // rows 512..599 into LDS (fp32, coalesced)
    for (int i = t; i < 88 * 200; i += 512) {
        int r = i / 200, k = i - r * 200;
        wlds[r][k] = W_hh[(size_t)(512 + r) * 200 + k];
    }
    for (int i = t; i < 600; i += 512) bsh[i] = b_hh[i];
    if (t < 200) hsh[t] = h1[((size_t)b * 201 + 200) * 200 + t];
    __syncthreads();

    const float4* hsh4 = reinterpret_cast<const float4*>(hsh);
    const int lr = t >> 1, lq = t & 1;

    for (int step = 0; step < TT; ++step) {
        float gr = 0.f, gz = 0.f, gn_ = 0.f, hold = 0.f;
        if (t < 200) {
            const float* girow = gi + ((size_t)b * TT + step) * G3 + t;
            gr  = girow[0];
            gz  = girow[200];
            gn_ = girow[400];
            hold = hsh[t];
        }

        // register-row dot (bf16 weights, fp32 h): output u = t
        float a0 = 0.f, a1 = 0.f, a2 = 0.f, a3 = 0.f;
        #pragma unroll
        for (int i = 0; i < 25; ++i) {
            uint4 w = wb[i];
            float4 h0 = hsh4[2 * i], h1v = hsh4[2 * i + 1];
            a0 += bflo(w.x) * h0.x;  a1 += bfhi(w.x) * h0.y;
            a2 += bflo(w.y) * h0.z;  a3 += bfhi(w.y) * h0.w;
            a0 += bflo(w.z) * h1v.x; a1 += bfhi(w.z) * h1v.y;
            a2 += bflo(w.w) * h1v.z; a3 += bfhi(w.w) * h1v.w;
        }
        pre[t] = (a0 + a1) + (a2 + a3);

        // LDS rows 512..599 (fp32), 2-way k-split
        if (t < 176) {
            const float4* wr4 = reinterpret_cast<const float4*>(&wlds[lr][lq * 100]);
            const float4* hh4 = hsh4 + lq * 25;
            float c0 = 0.f, c1 = 0.f, c2 = 0.f, c3 = 0.f;
            #pragma unroll
            for (int i = 0; i < 25; ++i) {
                float4 wvv = wr4[i];
                float4 hv  = hh4[i];
                c0 += wvv.x * hv.x;
                c1 += wvv.y * hv.y;
                c2 += wvv.z * hv.z;
                c3 += wvv.w * hv.w;
            }
            float cc = (c0 + c1) + (c2 + c3);
            cc += __shfl_xor(cc, 1);
            if (lq == 0) pre[512 + lr] = cc;
        }
        __syncthreads();

        if (t < 200) {
            float pr = gr  + pre[t]       + bsh[t];
            float pz = gz  + pre[200 + t] + bsh[200 + t];
            float hn = pre[400 + t] + bsh[400 + t];
            float r = 1.f / (1.f + __expf(-pr));
            float z = 1.f / (1.f + __expf(-pz));
            float n = tanhf(gn_ + r * hn);
            float hnew = (1.f - z) * n + z * hold;
            hsh[t] = hnew;
            h2[((size_t)b * TT + step) * 200 + t] = hnew;
        }
        __syncthreads();
    }
}

// ---------------------------------------------------------------- fused attention + gate
__global__ void __launch_bounds__(256) k_attn(const float* __restrict__ q,
                                              const float* __restrict__ kv,
                                              const float* __restrict__ h2,
                                              const float* __restrict__ W_gate,
                                              const float* __restrict__ b_gate,
                                              float* __restrict__ out,
                                              float* __restrict__ gbuf,
                                              unsigned short* __restrict__ s2b) {
    int row = blockIdx.x;
    int b = row / TT;
    int tid = threadIdx.x;
    __shared__ __align__(16) float qsh[200];
    __shared__ __align__(16) float h2sh[200];
    __shared__ float ash[200];
    __shared__ float csh[200];
    __shared__ float red[8];

    if (tid < 50) {
        reinterpret_cast<float4*>(qsh)[tid]  = reinterpret_cast<const float4*>(q  + (size_t)row * 200)[tid];
        reinterpret_cast<float4*>(h2sh)[tid] = reinterpret_cast<const float4*>(h2 + (size_t)row * 200)[tid];
    }
    __syncthreads();

    const float* kvb = kv + (size_t)b * 200 * 200;
    float dval = -__builtin_inff();
    if (tid < 200) {
        const float4* kr = reinterpret_cast<const float4*>(kvb + (size_t)tid * 200);
        float s = 0.f;
        #pragma unroll 5
        for (int k4 = 0; k4 < 50; ++k4) {
            float4 kvv = kr[k4];
            float4 qv = reinterpret_cast<float4*>(qsh)[k4];
            s += kvv.x * qv.x + kvv.y * qv.y + kvv.z * qv.z + kvv.w * qv.w;
        }
        dval = s * 0.07071067811865475f;  // 1/sqrt(200)
    }
    float m = dval;
    for (int o = 32; o; o >>= 1) m = fmaxf(m, __shfl_xor(m, o));
    if ((tid & 63) == 0) red[tid >> 6] = m;
    __syncthreads();
    m = fmaxf(fmaxf(red[0], red[1]), fmaxf(red[2], red[3]));
    float e = (tid < 200) ? __expf(dval - m) : 0.f;
    float ssum = e;
    for (int o = 32; o; o >>= 1) ssum += __shfl_xor(ssum, o);
    if ((tid & 63) == 0) red[4 + (tid >> 6)] = ssum;
    __syncthreads();
    float Ssum = red[4] + red[5] + red[6] + red[7];
    float logS = logf(Ssum);
    float p1v = dval - m - logS;
    if (tid < 200) ash[tid] = e / Ssum;
    __syncthreads();

    if (tid < 200) {
        float c = 0.f;
        #pragma unroll 4
        for (int s = 0; s < 200; ++s) c += ash[s] * kvb[(size_t)s * 200 + tid];
        csh[tid] = c;
    }
    __syncthreads();

    float gv = 0.f;
    if (tid < 200) gv = h2sh[tid] * W_gate[tid] + csh[tid] * W_gate[200 + tid];
    for (int o = 32; o; o >>= 1) gv += __shfl_xor(gv, o);
    if ((tid & 63) == 0) red[tid >> 6] = gv;
    __syncthreads();
    float g = red[0] + red[1] + red[2] + red[3] + b_gate[0];

    if (tid == 0) gbuf[row] = g;
    if (tid < 200) out[(size_t)row * OUTW + VV + tid] = (1.f - g) * p1v;

    if (tid < 208) {
        int k = tid * 2;
        float v0 = (k < 200) ? h2sh[k] : (k < 400) ? csh[k - 200] : 0.f;
        float v1 = (k + 1 < 200) ? h2sh[k + 1] : (k + 1 < 400) ? csh[k + 1 - 200] : 0.f;
        unsigned int pk = (unsigned int)f2bf(v0) | ((unsigned int)f2bf(v1) << 16);
        reinterpret_cast<unsigned int*>(s2b + (size_t)row * KP)[tid] = pk;
    }
}

// ---------------------------------------------------------------- big bf16 MFMA GEMM
__global__ void __launch_bounds__(256) k_gemm_big(int pass,
        const unsigned short* __restrict__ Ab, const unsigned short* __restrict__ Bb,
        const float* __restrict__ b_out, float2* __restrict__ partials,
        const float* __restrict__ logZs, const float* __restrict__ gbuf,
        float* __restrict__ out) {
    __shared__ __align__(16) unsigned short Ash[128 * 32];
    __shared__ __align__(16) unsigned short Bsh[128 * 32];
    __shared__ float redsh[128][2][2];
    __shared__ float zsh[128], gsh[128];

    const int m0 = blockIdx.x * 128, n0 = blockIdx.y * 128;
    const int tid = threadIdx.x;
    const int lane = tid & 63, wid = tid >> 6;
    const int wr = wid >> 1, wc = wid & 1;
    const int rq = lane >> 4, r15 = lane & 15;

    if (pass == 2 && tid < 128) {
        int gm = m0 + tid;
        zsh[tid] = (gm < NROWS) ? logZs[gm] : 0.f;
        gsh[tid] = (gm < NROWS) ? gbuf[gm] : 0.f;
    }

    const int c2 = tid + 256;
    const unsigned short* a1 = Ab + (size_t)(m0 + (tid >> 2)) * KP + (tid & 3) * 8;
    const unsigned short* a2 = Ab + (size_t)(m0 + (c2 >> 2)) * KP + (c2 & 3) * 8;
    const unsigned short* b1 = Bb + (size_t)(n0 + (tid >> 2)) * KP + (tid & 3) * 8;
    const unsigned short* b2 = Bb + (size_t)(n0 + (c2 >> 2)) * KP + (c2 & 3) * 8;
    unsigned short* ldsA1 = Ash + wid * 512;
    unsigned short* ldsA2 = Ash + wid * 512 + 2048;
    unsigned short* ldsB1 = Bsh + wid * 512;
    unsigned short* ldsB2 = Bsh + wid * 512 + 2048;

    f32x4 zero = {0.f, 0.f, 0.f, 0.f};
    f32x4 acc[4][4];
    #pragma unroll
    for (int i = 0; i < 4; ++i)
        #pragma unroll
        for (int j = 0; j < 4; ++j) acc[i][j] = zero;

    const bf16x8* A8 = reinterpret_cast<const bf16x8*>(Ash);
    const bf16x8* B8 = reinterpret_cast<const bf16x8*>(Bsh);

    for (int kt = 0; kt < KP / 32; ++kt) {
        const int ko = kt * 32;
        gl_lds16(a1 + ko, ldsA1);
        gl_lds16(a2 + ko, ldsA2);
        gl_lds16(b1 + ko, ldsB1);
        gl_lds16(b2 + ko, ldsB2);
        __syncthreads();
        bf16x8 af[4], bfr[4];
        #pragma unroll
        for (int mi = 0; mi < 4; ++mi) af[mi] = A8[(wr * 64 + mi * 16 + r15) * 4 + rq];
        #pragma unroll
        for (int ni = 0; ni < 4; ++ni) bfr[ni] = B8[(wc * 64 + ni * 16 + r15) * 4 + rq];
        #pragma unroll
        for (int mi = 0; mi < 4; ++mi)
            #pragma unroll
            for (int ni = 0; ni < 4; ++ni)
                acc[mi][ni] = __builtin_amdgcn_mfma_f32_16x16x32_bf16(af[mi], bfr[ni], acc[mi][ni], 0, 0, 0);
        __syncthreads();
    }

    float bias[4]; bool nok[4]; int gn[4];
    #pragma unroll
    for (int ni = 0; ni < 4; ++ni) {
        gn[ni] = n0 + wc * 64 + ni * 16 + r15;
        nok[ni] = gn[ni] < VV;
        bias[ni] = nok[ni] ? b_out[gn[ni]] : 0.f;
    }

    if (pass == 1) {
        #pragma unroll
        for (int mi = 0; mi < 4; ++mi) {
            #pragma unroll
            for (int r = 0; r < 4; ++r) {
                float v[4]; float mx = -__builtin_inff();
                #pragma unroll
                for (int ni = 0; ni < 4; ++ni) {
                    v[ni] = nok[ni] ? (acc[mi][ni][r] + bias[ni]) : -__builtin_inff();
                    mx = fmaxf(mx, v[ni]);
                }
                #pragma unroll
                for (int o = 1; o < 16; o <<= 1) mx = fmaxf(mx, __shfl_xor(mx, o));
                float se = 0.f;
                #pragma unroll
                for (int ni = 0; ni < 4; ++ni) se += nok[ni] ? __expf(v[ni] - mx) : 0.f;
                #pragma unroll
                for (int o = 1; o < 16; o <<= 1) se += __shfl_xor(se, o);
                int ml = wr * 64 + mi * 16 + rq * 4 + r;
                if (r15 == 0) { redsh[ml][wc][0] = mx; redsh[ml][wc][1] = se; }
            }
        }
        __syncthreads();
        if (tid < 128) {
            float m1 = redsh[tid][0][0], s1 = redsh[tid][0][1];
            float m2 = redsh[tid][1][0], s2 = redsh[tid][1][1];
            float mm = fmaxf(m1, m2);
            float ss = s1 * __expf(m1 - mm) + s2 * __expf(m2 - mm);
            partials[(size_t)(m0 + tid) * NTILES + blockIdx.y] = float2{mm, ss};
        }
    } else {
        #pragma unroll
        for (int mi = 0; mi < 4; ++mi) {
            #pragma unroll
            for (int r = 0; r < 4; ++r) {
                int ml = wr * 64 + mi * 16 + rq * 4 + r;
                int gm = m0 + ml;
                if (gm < NROWS) {
                    float gz = gsh[ml], lz = zsh[ml];
                    #pragma unroll
                    for (int ni = 0; ni < 4; ++ni)
                        if (nok[ni])
                            out[(size_t)gm * OUTW + gn[ni]] = gz * (acc[mi][ni][r] + bias[ni] - lz);
                }
            }
        }
    }
}

// ---------------------------------------------------------------- row reduce -> logZ
__global__ void __launch_bounds__(128) k_rowred(const float2* __restrict__ partials,
                                                float* __restrict__ logZs) {
    int row = blockIdx.x;
    int tid = threadIdx.x;
    float m = -__builtin_inff(), s = 0.f;
    for (int t = tid; t < NTILES; t += 128) {
        float2 p = partials[(size_t)row * NTILES + t];
        if (p.y > 0.f) {
            float nm = fmaxf(m, p.x);
            s = s * __expf(m - nm) + p.y * __expf(p.x - nm);
            m = nm;
        }
    }
    for (int o = 32; o; o >>= 1) {
        float om = __shfl_xor(m, o), os = __shfl_xor(s, o);
        float nm = fmaxf(m, om);
        s = s * __expf(m - nm) + os * __expf(om - nm);
        m = nm;
    }
    __shared__ float ms[2], ss[2];
    if ((tid & 63) == 0) { ms[tid >> 6] = m; ss[tid >> 6] = s; }
    __syncthreads();
    if (tid == 0) {
        float nm = fmaxf(ms[0], ms[1]);
        float S = ss[0] * __expf(ms[0] - nm) + ss[1] * __expf(ms[1] - nm);
        logZs[row] = nm + logf(S);
    }
}

// ----------------------------------------------------------------
extern "C" void kernel_launch(void* const* d_in, const int* in_sizes, int n_in,
                              void* d_out, int out_size, void* d_ws, size_t ws_size,
                              hipStream_t stream) {
    const int*   y      = (const int*)  d_in[0];
    const float* h1     = (const float*)d_in[1];
    const float* embed  = (const float*)d_in[2];
    const float* W_ih   = (const float*)d_in[3];
    const float* W_hh   = (const float*)d_in[4];
    const float* b_ih   = (const float*)d_in[5];
    const float* b_hh   = (const float*)d_in[6];
    const float* W_attn = (const float*)d_in[7];
    const float* b_attn = (const float*)d_in[8];
    const float* W_gate = (const float*)d_in[9];
    const float* b_gate = (const float*)d_in[10];
    const float* W_out  = (const float*)d_in[11];
    const float* b_out  = (const float*)d_in[12];
    float* out = (float*)d_out;

    char* wp = (char*)d_ws;
    auto alloc = [&](size_t bytes) {
        char* p = wp;
        wp += (bytes + 255) & ~(size_t)255;
        return p;
    };
    float* gi     = (float*)alloc((size_t)NROWS * G3 * 4);
    float* h2     = (float*)alloc((size_t)NROWS * HIDN * 4);
    float* wattnT = (float*)alloc((size_t)200 * 200 * 4);
    float* q      = (float*)alloc((size_t)NROWS * 200 * 4);
    float* kv     = (float*)alloc((size_t)BB * 200 * 200 * 4);
    float* gbuf   = (float*)alloc((size_t)NROWS * 4);
    float* logZs  = (float*)alloc((size_t)NROWS * 4);
    float2* partials      = (float2*)alloc((size_t)MP * NTILES * 8);
    unsigned short* s2b   = (unsigned short*)alloc((size_t)MP * KP * 2);
    unsigned short* woutT = (unsigned short*)alloc((size_t)NP * KP * 2);

    k_wattnT<<<dim3(157), dim3(256), 0, stream>>>(W_attn, wattnT);
    k_small_gemm<1><<<dim3(25, 19), dim3(256), 0, stream>>>(embed, W_ih, b_ih, gi, y, NROWS, G3);
    k_gru_wout<<<dim3(BB + WBLKS), dim3(512), 0, stream>>>(gi, W_hh, b_hh, h1, h2, W_out, woutT);
    k_small_gemm<0><<<dim3(25, 7),  dim3(256), 0, stream>>>(h2, wattnT, b_attn, q,  nullptr, NROWS, 200);
    k_small_gemm<2><<<dim3(100, 7), dim3(256), 0, stream>>>(h1, wattnT, b_attn, kv, nullptr, BB * 200, 200);
    k_attn<<<dim3(NROWS), dim3(256), 0, stream>>>(q, kv, h2, W_gate, b_gate, out, gbuf, s2b);
    k_gemm_big<<<dim3(MTILES, NTILES), dim3(256), 0, stream>>>(1, s2b, woutT, b_out, partials, logZs, gbuf, out);
    k_rowred<<<dim3(NROWS), dim3(128), 0, stream>>>(partials, logZs);
    k_gemm_big<<<dim3(MTILES, NTILES), dim3(256), 0, stream>>>(2, s2b, woutT, b_out, partials, logZs, gbuf, out);
}